// Round 1
// baseline (347.117 us; speedup 1.0000x reference)
//
#include <hip/hip_runtime.h>

typedef unsigned short u16;
typedef float f32x4 __attribute__((ext_vector_type(4)));
typedef __bf16 bf16x8 __attribute__((ext_vector_type(8)));
typedef short short8 __attribute__((ext_vector_type(8)));
typedef u16 u16x4 __attribute__((ext_vector_type(4)));
typedef float f32x4v __attribute__((ext_vector_type(4)));

#define DEV __device__ __forceinline__

DEV u16 f2bf(float f) {
    union { float f; unsigned u; } v; v.f = f;
    unsigned r = v.u + 0x7FFFu + ((v.u >> 16) & 1u);
    return (u16)(r >> 16);
}

DEV void gload_lds16(const u16* g, u16* l) {
    __builtin_amdgcn_global_load_lds(
        (const __attribute__((address_space(1))) void*)g,
        (__attribute__((address_space(3))) void*)l, 16, 0, 0);
}

// ---------------- convert fp32 -> bf16 (vectorized) ----------------
__global__ __launch_bounds__(256) void k_cvt(const float* __restrict__ in,
                                             u16* __restrict__ out, int n4) {
    int i = blockIdx.x * 256 + threadIdx.x;
    if (i >= n4) return;
    f32x4v v = reinterpret_cast<const f32x4v*>(in)[i];
    u16x4 o;
    o.x = f2bf(v.x); o.y = f2bf(v.y); o.z = f2bf(v.z); o.w = f2bf(v.w);
    reinterpret_cast<u16x4*>(out)[i] = o;
}

// ---------------- convert + transpose: in[R][C] f32 -> out[C][R] bf16 ----------------
__global__ __launch_bounds__(256) void k_transpose_cvt(const float* __restrict__ in,
                                                       u16* __restrict__ out,
                                                       int R, int C) {
    __shared__ float tile[32][33];
    const int c0 = blockIdx.x * 32, r0 = blockIdx.y * 32;
    const int tx = threadIdx.x & 31, ty = threadIdx.x >> 5;  // ty 0..7
#pragma unroll
    for (int i = 0; i < 32; i += 8)
        tile[ty + i][tx] = in[(size_t)(r0 + ty + i) * C + c0 + tx];
    __syncthreads();
#pragma unroll
    for (int i = 0; i < 32; i += 8)
        out[(size_t)(c0 + ty + i) * R + r0 + tx] = f2bf(tile[tx][ty + i]);
}

// ---------------- bf16 GEMM: C[M][N] = A[M][K] * Bt[N][K]^T ----------------
// 128x128 tile, BK=32, 256 threads (4 waves, 2x2 of 64x64), mfma 16x16x32 bf16.
template <int OUTF>  // 0: bf16 out, 1: f32 out
__global__ __launch_bounds__(256) void k_gemm_nt(const u16* __restrict__ A,
                                                 const u16* __restrict__ Bt,
                                                 void* __restrict__ Cv,
                                                 int M, int N, int K) {
    __shared__ u16 lA[2][4096];  // [128][32]
    __shared__ u16 lB[2][4096];  // [128][32]
    const int t = threadIdx.x, l = t & 63, w = t >> 6;
    const int bm = blockIdx.y * 128, bn = blockIdx.x * 128;
    const int wr = w >> 1, wc = w & 1;
    const int lm = l & 15, lg = l >> 4;

    f32x4 acc[4][4] = {};

    const int nk = K >> 5;
    auto stage = [&](int buf, int kt) {
        const int k0 = kt << 5;
        const int kc = (l & 3) * 8;
        const int rsub = w * 16 + (l >> 2);
#pragma unroll
        for (int p = 0; p < 2; ++p) {
            const int row = p * 64 + rsub;
            gload_lds16(A + (size_t)(bm + row) * K + k0 + kc, &lA[buf][p * 2048 + w * 512]);
            gload_lds16(Bt + (size_t)(bn + row) * K + k0 + kc, &lB[buf][p * 2048 + w * 512]);
        }
    };

    stage(0, 0);
    __syncthreads();
    for (int kt = 0; kt < nk; ++kt) {
        const int buf = kt & 1;
        if (kt + 1 < nk) stage(buf ^ 1, kt + 1);
        bf16x8 af[4], bfr[4];
#pragma unroll
        for (int i = 0; i < 4; ++i) {
            af[i]  = *reinterpret_cast<const bf16x8*>(&lA[buf][(wr * 64 + i * 16 + lm) * 32 + lg * 8]);
            bfr[i] = *reinterpret_cast<const bf16x8*>(&lB[buf][(wc * 64 + i * 16 + lm) * 32 + lg * 8]);
        }
#pragma unroll
        for (int mi = 0; mi < 4; ++mi)
#pragma unroll
            for (int ni = 0; ni < 4; ++ni)
                acc[mi][ni] = __builtin_amdgcn_mfma_f32_16x16x32_bf16(af[mi], bfr[ni], acc[mi][ni], 0, 0, 0);
        __syncthreads();
    }

#pragma unroll
    for (int mi = 0; mi < 4; ++mi)
#pragma unroll
        for (int ni = 0; ni < 4; ++ni)
#pragma unroll
            for (int r = 0; r < 4; ++r) {
                const int row = bm + wr * 64 + mi * 16 + lg * 4 + r;
                const int col = bn + wc * 64 + ni * 16 + lm;
                if (OUTF)
                    reinterpret_cast<float*>(Cv)[(size_t)row * N + col] = acc[mi][ni][r];
                else
                    reinterpret_cast<u16*>(Cv)[(size_t)row * N + col] = f2bf(acc[mi][ni][r]);
            }
}

// ---------------- flash attention with ALiBi + causal ----------------
// qkv: [4096][4096] bf16 rows = b*1024+s; cols: [0,2048) Q, [2048,3072) K, [3072,4096) V
// AO:  [4096][2048] bf16  (b,s, hq, d)
__global__ __launch_bounds__(256) void k_attn(const u16* __restrict__ qkv,
                                              u16* __restrict__ AO) {
    __shared__ u16 lQ[8192];      // [128][64]
    __shared__ u16 lK[4096];      // [64][64]
    __shared__ u16 lVT[4096];     // [64 d][64 kv]
    __shared__ u16 lP[4][2048];   // per-wave [32 q][64 kv]

    const int t = threadIdx.x, l = t & 63, w = t >> 6;
    const int lm = l & 15, lg = l >> 4;
    const int qb = blockIdx.x;   // 0..7
    const int hq = blockIdx.y;   // 0..31
    const int b  = blockIdx.z;   // 0..3
    const int hkv = hq >> 1;
    const float slope = exp2f(-0.25f * (float)(hq + 1));

    const size_t RS = 4096;
    const u16* Qg = qkv + (size_t)(b * 1024 + qb * 128) * RS + hq * 64;
    const u16* Kg = qkv + (size_t)(b * 1024) * RS + 2048 + hkv * 64;
    const u16* Vg = qkv + (size_t)(b * 1024) * RS + 3072 + hkv * 64;

    // stage Q (128x64) once
    {
        const int rr = w * 8 + (l >> 3);
        const int dc = (l & 7) * 8;
#pragma unroll
        for (int p = 0; p < 4; ++p)
            gload_lds16(Qg + (size_t)(p * 32 + rr) * RS + dc, &lQ[p * 2048 + w * 512]);
    }

    float m_s[2][4], l_s[2][4];
    f32x4 acc_o[2][4] = {};
#pragma unroll
    for (int qf = 0; qf < 2; ++qf)
#pragma unroll
        for (int r = 0; r < 4; ++r) { m_s[qf][r] = -1e30f; l_s[qf][r] = 0.f; }

    const int kbmax = qb * 2 + 1;
    const int qmax = qb * 128 + w * 32 + 31;  // wave-uniform

    for (int kb = 0; kb <= kbmax; ++kb) {
        // stage K tile [64][64] via global_load_lds (linear dest)
        {
            const int rr = w * 8 + (l >> 3);
            const int dc = (l & 7) * 8;
#pragma unroll
            for (int p = 0; p < 2; ++p)
                gload_lds16(Kg + (size_t)(kb * 64 + p * 32 + rr) * RS + dc, &lK[p * 2048 + w * 512]);
        }
        // stage V^T tile [64 d][64 kv] via register transpose
        {
#pragma unroll
            for (int p = 0; p < 2; ++p) {
                const int kv = p * 32 + (t >> 3);
                const int d0 = (t & 7) * 8;
                short8 v = *reinterpret_cast<const short8*>(Vg + (size_t)(kb * 64 + kv) * RS + d0);
#pragma unroll
                for (int j = 0; j < 8; ++j)
                    lVT[(d0 + j) * 64 + kv] = (u16)v[j];
            }
        }
        __syncthreads();

        if (kb * 64 <= qmax) {
            // QK^T: scores[32 q][64 kv] per wave
            f32x4 sc[2][4] = {};
#pragma unroll
            for (int ks = 0; ks < 2; ++ks) {
                bf16x8 aq[2], bk[4];
#pragma unroll
                for (int qf = 0; qf < 2; ++qf)
                    aq[qf] = *reinterpret_cast<const bf16x8*>(&lQ[(w * 32 + qf * 16 + lm) * 64 + ks * 32 + lg * 8]);
#pragma unroll
                for (int kf = 0; kf < 4; ++kf)
                    bk[kf] = *reinterpret_cast<const bf16x8*>(&lK[(kf * 16 + lm) * 64 + ks * 32 + lg * 8]);
#pragma unroll
                for (int qf = 0; qf < 2; ++qf)
#pragma unroll
                    for (int kf = 0; kf < 4; ++kf)
                        sc[qf][kf] = __builtin_amdgcn_mfma_f32_16x16x32_bf16(aq[qf], bk[kf], sc[qf][kf], 0, 0, 0);
            }
            // online softmax; D layout: row q = lg*4+r (+qf*16), col kv = lm (+kf*16)
#pragma unroll
            for (int qf = 0; qf < 2; ++qf) {
#pragma unroll
                for (int r = 0; r < 4; ++r) {
                    const int q = qb * 128 + w * 32 + qf * 16 + lg * 4 + r;
                    float vals[4];
                    float mx = -1e30f;
#pragma unroll
                    for (int kf = 0; kf < 4; ++kf) {
                        const int kv = kb * 64 + kf * 16 + lm;
                        float v = sc[qf][kf][r] * 0.125f + slope * (float)(kv - q);
                        if (kv > q) v = -1e30f;
                        vals[kf] = v;
                        mx = fmaxf(mx, v);
                    }
                    mx = fmaxf(mx, __shfl_xor(mx, 1));
                    mx = fmaxf(mx, __shfl_xor(mx, 2));
                    mx = fmaxf(mx, __shfl_xor(mx, 4));
                    mx = fmaxf(mx, __shfl_xor(mx, 8));
                    const float mold = m_s[qf][r];
                    const float mnew = fmaxf(mold, mx);
                    const float scl = __expf(mold - mnew);
                    m_s[qf][r] = mnew;
                    float ps = 0.f;
                    const int qloc = qf * 16 + lg * 4 + r;
#pragma unroll
                    for (int kf = 0; kf < 4; ++kf) {
                        float p = __expf(vals[kf] - mnew);
                        ps += p;
                        lP[w][qloc * 64 + kf * 16 + lm] = f2bf(p);
                    }
                    ps += __shfl_xor(ps, 1);
                    ps += __shfl_xor(ps, 2);
                    ps += __shfl_xor(ps, 4);
                    ps += __shfl_xor(ps, 8);
                    l_s[qf][r] = l_s[qf][r] * scl + ps;
#pragma unroll
                    for (int df = 0; df < 4; ++df)
                        acc_o[qf][df][r] *= scl;
                }
            }
            // same-wave LDS write->read fence (DS in-order + drain)
            asm volatile("s_waitcnt lgkmcnt(0)" ::: "memory");
            // PV: O[32 q][64 d] += P[32 q][64 kv] * V[64 kv][64 d]
#pragma unroll
            for (int ks = 0; ks < 2; ++ks) {
                bf16x8 ap[2], bv[4];
#pragma unroll
                for (int qf = 0; qf < 2; ++qf)
                    ap[qf] = *reinterpret_cast<const bf16x8*>(&lP[w][(qf * 16 + lm) * 64 + ks * 32 + lg * 8]);
#pragma unroll
                for (int df = 0; df < 4; ++df)
                    bv[df] = *reinterpret_cast<const bf16x8*>(&lVT[(df * 16 + lm) * 64 + ks * 32 + lg * 8]);
#pragma unroll
                for (int qf = 0; qf < 2; ++qf)
#pragma unroll
                    for (int df = 0; df < 4; ++df)
                        acc_o[qf][df] = __builtin_amdgcn_mfma_f32_16x16x32_bf16(ap[qf], bv[df], acc_o[qf][df], 0, 0, 0);
            }
        }
        __syncthreads();
    }

    // epilogue: normalize and store bf16
#pragma unroll
    for (int qf = 0; qf < 2; ++qf)
#pragma unroll
        for (int r = 0; r < 4; ++r) {
            const float invl = 1.f / l_s[qf][r];
            const int q = qb * 128 + w * 32 + qf * 16 + lg * 4 + r;
#pragma unroll
            for (int df = 0; df < 4; ++df)
                AO[(size_t)(b * 1024 + q) * 2048 + hq * 64 + df * 16 + lm] = f2bf(acc_o[qf][df][r] * invl);
        }
}

// ---------------- host ----------------
extern "C" void kernel_launch(void* const* d_in, const int* in_sizes, int n_in,
                              void* d_out, int out_size, void* d_ws, size_t ws_size,
                              hipStream_t stream) {
    const float* X    = (const float*)d_in[0];  // [4096][1024]
    const float* Wqkv = (const float*)d_in[1];  // [1024][4096]
    const float* Wout = (const float*)d_in[2];  // [2048][1024]
    float* out = (float*)d_out;                 // [4096][1024]

    char* ws = (char*)d_ws;
    u16* Xb    = (u16*)(ws);                      // 8 MB  [4096][1024]
    u16* WqkvT = (u16*)(ws + (size_t)(8  << 20)); // 8 MB  [4096][1024]
    u16* WoutT = (u16*)(ws + (size_t)(16 << 20)); // 4 MB  [1024][2048]
    u16* QKV   = (u16*)(ws + (size_t)(20 << 20)); // 32 MB [4096][4096]
    u16* AO    = (u16*)(ws + (size_t)(52 << 20)); // 16 MB [4096][2048]

    k_cvt<<<4096, 256, 0, stream>>>(X, Xb, (4096 * 1024) / 4);
    k_transpose_cvt<<<dim3(128, 32), 256, 0, stream>>>(Wqkv, WqkvT, 1024, 4096);
    k_transpose_cvt<<<dim3(32, 64), 256, 0, stream>>>(Wout, WoutT, 2048, 1024);

    // QKV = Xb[4096,1024] @ WqkvT^T -> bf16 [4096][4096]
    k_gemm_nt<0><<<dim3(32, 32), 256, 0, stream>>>(Xb, WqkvT, QKV, 4096, 4096, 1024);

    // attention -> AO bf16 [4096][2048]
    k_attn<<<dim3(8, 32, 4), 256, 0, stream>>>(QKV, AO);

    // out = AO[4096,2048] @ WoutT^T -> f32 [4096][1024]
    k_gemm_nt<1><<<dim3(8, 32), 256, 0, stream>>>(AO, WoutT, out, 4096, 1024, 2048);
}

// Round 3
// 299.120 us; speedup vs baseline: 1.1605x; 1.1605x over previous
//
#include <hip/hip_runtime.h>

typedef unsigned short u16;
typedef float f32x4 __attribute__((ext_vector_type(4)));
typedef __bf16 bf16x8 __attribute__((ext_vector_type(8)));
typedef short short8 __attribute__((ext_vector_type(8)));
typedef u16 u16x4 __attribute__((ext_vector_type(4)));
typedef float f32x4v __attribute__((ext_vector_type(4)));

#define DEV __device__ __forceinline__

DEV u16 f2bf(float f) {
    union { float f; unsigned u; } v; v.f = f;
    unsigned r = v.u + 0x7FFFu + ((v.u >> 16) & 1u);
    return (u16)(r >> 16);
}

DEV void gload_lds16(const u16* g, u16* l) {
    __builtin_amdgcn_global_load_lds(
        (const __attribute__((address_space(1))) void*)g,
        (__attribute__((address_space(3))) void*)l, 16, 0, 0);
}

// ---------------- convert fp32 -> bf16 (vectorized) ----------------
__global__ __launch_bounds__(256) void k_cvt(const float* __restrict__ in,
                                             u16* __restrict__ out, int n4) {
    int i = blockIdx.x * 256 + threadIdx.x;
    if (i >= n4) return;
    f32x4v v = reinterpret_cast<const f32x4v*>(in)[i];
    u16x4 o;
    o.x = f2bf(v.x); o.y = f2bf(v.y); o.z = f2bf(v.z); o.w = f2bf(v.w);
    reinterpret_cast<u16x4*>(out)[i] = o;
}

// ---------------- convert + transpose: in[R][C] f32 -> out[C][R] bf16 ----------------
__global__ __launch_bounds__(256) void k_transpose_cvt(const float* __restrict__ in,
                                                       u16* __restrict__ out,
                                                       int R, int C) {
    __shared__ float tile[32][33];
    const int c0 = blockIdx.x * 32, r0 = blockIdx.y * 32;
    const int tx = threadIdx.x & 31, ty = threadIdx.x >> 5;  // ty 0..7
#pragma unroll
    for (int i = 0; i < 32; i += 8)
        tile[ty + i][tx] = in[(size_t)(r0 + ty + i) * C + c0 + tx];
    __syncthreads();
#pragma unroll
    for (int i = 0; i < 32; i += 8)
        out[(size_t)(c0 + ty + i) * R + r0 + tx] = f2bf(tile[tx][ty + i]);
}

// ---------------- bf16 GEMM: C[M][N] = A[M][K] * Bt[N][K]^T ----------------
// 128x128 tile, BK=32, 256 threads (4 waves, 2x2 of 64x64), mfma 16x16x32 bf16.
template <int OUTF>  // 0: bf16 out, 1: f32 out
__global__ __launch_bounds__(256) void k_gemm_nt(const u16* __restrict__ A,
                                                 const u16* __restrict__ Bt,
                                                 void* __restrict__ Cv,
                                                 int M, int N, int K) {
    __shared__ u16 lA[2][4096];  // [128][32]
    __shared__ u16 lB[2][4096];  // [128][32]
    const int t = threadIdx.x, l = t & 63, w = t >> 6;
    const int bm = blockIdx.y * 128, bn = blockIdx.x * 128;
    const int wr = w >> 1, wc = w & 1;
    const int lm = l & 15, lg = l >> 4;

    f32x4 acc[4][4] = {};

    const int nk = K >> 5;
    auto stage = [&](int buf, int kt) {
        const int k0 = kt << 5;
        const int kc = (l & 3) * 8;
        const int rsub = w * 16 + (l >> 2);
#pragma unroll
        for (int p = 0; p < 2; ++p) {
            const int row = p * 64 + rsub;
            gload_lds16(A + (size_t)(bm + row) * K + k0 + kc, &lA[buf][p * 2048 + w * 512]);
            gload_lds16(Bt + (size_t)(bn + row) * K + k0 + kc, &lB[buf][p * 2048 + w * 512]);
        }
    };

    stage(0, 0);
    __syncthreads();
    for (int kt = 0; kt < nk; ++kt) {
        const int buf = kt & 1;
        if (kt + 1 < nk) stage(buf ^ 1, kt + 1);
        bf16x8 af[4], bfr[4];
#pragma unroll
        for (int i = 0; i < 4; ++i) {
            af[i]  = *reinterpret_cast<const bf16x8*>(&lA[buf][(wr * 64 + i * 16 + lm) * 32 + lg * 8]);
            bfr[i] = *reinterpret_cast<const bf16x8*>(&lB[buf][(wc * 64 + i * 16 + lm) * 32 + lg * 8]);
        }
        __builtin_amdgcn_s_setprio(1);
#pragma unroll
        for (int mi = 0; mi < 4; ++mi)
#pragma unroll
            for (int ni = 0; ni < 4; ++ni)
                acc[mi][ni] = __builtin_amdgcn_mfma_f32_16x16x32_bf16(af[mi], bfr[ni], acc[mi][ni], 0, 0, 0);
        __builtin_amdgcn_s_setprio(0);
        __syncthreads();
    }

#pragma unroll
    for (int mi = 0; mi < 4; ++mi)
#pragma unroll
        for (int ni = 0; ni < 4; ++ni)
#pragma unroll
            for (int r = 0; r < 4; ++r) {
                const int row = bm + wr * 64 + mi * 16 + lg * 4 + r;
                const int col = bn + wc * 64 + ni * 16 + lm;
                if (OUTF)
                    reinterpret_cast<float*>(Cv)[(size_t)row * N + col] = acc[mi][ni][r];
                else
                    reinterpret_cast<u16*>(Cv)[(size_t)row * N + col] = f2bf(acc[mi][ni][r]);
            }
}

// ---------------- flash attention with ALiBi + causal ----------------
// qkv: [4096][4096] bf16 rows = b*1024+s; cols: [0,2048) Q, [2048,3072) K, [3072,4096) V
// AO:  [4096][2048] bf16  (b,s, hq, d)
// LDS tiles XOR-swizzled at 16B-chunk granularity to kill the 128B-row-stride
// bank conflicts (16-way on every ds_read_b128 otherwise).
//   lK : [64][64] u16, key = row & 7          (staged via pre-swizzled gload_lds src)
//   lVT: [64 d][64 kv], key = (d ^ (d>>3))&7  (reg-transpose writes + frag reads both <=2-way)
//   lP : per-wave [32 q][64 kv], key = q & 7
__global__ __launch_bounds__(256) void k_attn(const u16* __restrict__ qkv,
                                              u16* __restrict__ AO) {
    __shared__ u16 lK[4096];
    __shared__ u16 lVT[4096];
    __shared__ u16 lP[4][2048];

    const int t = threadIdx.x, l = t & 63, w = t >> 6;
    const int lm = l & 15, lg = l >> 4;
    const int qb = blockIdx.x;   // 0..7
    const int hq = blockIdx.y;   // 0..31
    const int b  = blockIdx.z;   // 0..3
    const int hkv = hq >> 1;
    const float slope = exp2f(-0.25f * (float)(hq + 1));

    const size_t RS = 4096;
    const u16* Qg = qkv + (size_t)(b * 1024 + qb * 128) * RS + hq * 64;
    const u16* Kg = qkv + (size_t)(b * 1024) * RS + 2048 + hkv * 64;
    const u16* Vg = qkv + (size_t)(b * 1024) * RS + 3072 + hkv * 64;

    // ---- Q hoisted to registers: lane holds Q[row = w*32+qf*16+lm][ks*32+lg*8 ..+8]
    bf16x8 aq[2][2];
#pragma unroll
    for (int qf = 0; qf < 2; ++qf)
#pragma unroll
        for (int ks = 0; ks < 2; ++ks)
            aq[qf][ks] = *reinterpret_cast<const bf16x8*>(
                Qg + (size_t)(w * 32 + qf * 16 + lm) * RS + ks * 32 + lg * 8);

    float m_s[2][4], l_s[2][4];
    f32x4 acc_o[2][4] = {};
#pragma unroll
    for (int qf = 0; qf < 2; ++qf)
#pragma unroll
        for (int r = 0; r < 4; ++r) { m_s[qf][r] = -1e30f; l_s[qf][r] = 0.f; }

    const int kbmax = qb * 2 + 1;
    const int qmax = qb * 128 + w * 32 + 31;  // wave-uniform

    for (int kb = 0; kb <= kbmax; ++kb) {
        // stage K tile [64][64]: linear LDS dest, pre-swizzled global chunk
        {
            const int rr = w * 8 + (l >> 3);       // row within 32-row half
            const int ch = l & 7;                  // dest 16B chunk within row
#pragma unroll
            for (int p = 0; p < 2; ++p) {
                const int row = p * 32 + rr;
                const int sc_ = ch ^ (row & 7);    // swizzled source chunk
                gload_lds16(Kg + (size_t)(kb * 64 + row) * RS + sc_ * 8,
                            &lK[p * 2048 + w * 512]);
            }
        }
        // stage V^T tile [64 d][64 kv] via register transpose, swizzled writes
        {
#pragma unroll
            for (int p = 0; p < 2; ++p) {
                const int kv = p * 32 + (t >> 3);
                const int d0 = (t & 7) * 8;
                short8 v = *reinterpret_cast<const short8*>(Vg + (size_t)(kb * 64 + kv) * RS + d0);
#pragma unroll
                for (int j = 0; j < 8; ++j) {
                    const int d = d0 + j;
                    const int key = (d ^ (d >> 3)) & 7;
                    lVT[d * 64 + (((kv >> 3) ^ key) & 7) * 8 + (kv & 7)] = (u16)v[j];
                }
            }
        }
        __syncthreads();

        if (kb * 64 <= qmax) {
            // QK^T: scores[32 q][64 kv] per wave
            f32x4 sc[2][4] = {};
#pragma unroll
            for (int ks = 0; ks < 2; ++ks) {
                bf16x8 bk[4];
#pragma unroll
                for (int kf = 0; kf < 4; ++kf) {
                    const int row = kf * 16 + lm;
                    bk[kf] = *reinterpret_cast<const bf16x8*>(
                        &lK[row * 64 + (((ks * 4 + lg) ^ (row & 7)) & 7) * 8]);
                }
                __builtin_amdgcn_s_setprio(1);
#pragma unroll
                for (int qf = 0; qf < 2; ++qf)
#pragma unroll
                    for (int kf = 0; kf < 4; ++kf)
                        sc[qf][kf] = __builtin_amdgcn_mfma_f32_16x16x32_bf16(aq[qf][ks], bk[kf], sc[qf][kf], 0, 0, 0);
                __builtin_amdgcn_s_setprio(0);
            }
            // online softmax; D layout: row q = lg*4+r (+qf*16), col kv = lm (+kf*16)
#pragma unroll
            for (int qf = 0; qf < 2; ++qf) {
#pragma unroll
                for (int r = 0; r < 4; ++r) {
                    const int q = qb * 128 + w * 32 + qf * 16 + lg * 4 + r;
                    float vals[4];
                    float mx = -1e30f;
#pragma unroll
                    for (int kf = 0; kf < 4; ++kf) {
                        const int kv = kb * 64 + kf * 16 + lm;
                        float v = sc[qf][kf][r] * 0.125f + slope * (float)(kv - q);
                        if (kv > q) v = -1e30f;
                        vals[kf] = v;
                        mx = fmaxf(mx, v);
                    }
                    mx = fmaxf(mx, __shfl_xor(mx, 1));
                    mx = fmaxf(mx, __shfl_xor(mx, 2));
                    mx = fmaxf(mx, __shfl_xor(mx, 4));
                    mx = fmaxf(mx, __shfl_xor(mx, 8));
                    const float mold = m_s[qf][r];
                    const float mnew = fmaxf(mold, mx);
                    const float scl = __expf(mold - mnew);
                    m_s[qf][r] = mnew;
                    float ps = 0.f;
                    const int qloc = qf * 16 + lg * 4 + r;
                    const int key = qloc & 7;
#pragma unroll
                    for (int kf = 0; kf < 4; ++kf) {
                        float p = __expf(vals[kf] - mnew);
                        ps += p;
                        lP[w][qloc * 64 + (((kf * 2 + (lm >> 3)) ^ key) & 7) * 8 + (lm & 7)] = f2bf(p);
                    }
                    ps += __shfl_xor(ps, 1);
                    ps += __shfl_xor(ps, 2);
                    ps += __shfl_xor(ps, 4);
                    ps += __shfl_xor(ps, 8);
                    l_s[qf][r] = l_s[qf][r] * scl + ps;
#pragma unroll
                    for (int df = 0; df < 4; ++df)
                        acc_o[qf][df][r] *= scl;
                }
            }
            // same-wave LDS write->read fence (DS in-order + drain)
            asm volatile("s_waitcnt lgkmcnt(0)" ::: "memory");
            // PV: O[32 q][64 d] += P[32 q][64 kv] * V[64 kv][64 d]
#pragma unroll
            for (int ks = 0; ks < 2; ++ks) {
                bf16x8 ap[2], bv[4];
#pragma unroll
                for (int qf = 0; qf < 2; ++qf) {
                    const int row = qf * 16 + lm;
                    ap[qf] = *reinterpret_cast<const bf16x8*>(
                        &lP[w][row * 64 + (((ks * 4 + lg) ^ (row & 7)) & 7) * 8]);
                }
#pragma unroll
                for (int df = 0; df < 4; ++df) {
                    const int d = df * 16 + lm;
                    const int key = (d ^ (d >> 3)) & 7;
                    bv[df] = *reinterpret_cast<const bf16x8*>(
                        &lVT[d * 64 + (((ks * 4 + lg) ^ key) & 7) * 8]);
                }
                __builtin_amdgcn_s_setprio(1);
#pragma unroll
                for (int qf = 0; qf < 2; ++qf)
#pragma unroll
                    for (int df = 0; df < 4; ++df)
                        acc_o[qf][df] = __builtin_amdgcn_mfma_f32_16x16x32_bf16(ap[qf], bv[df], acc_o[qf][df], 0, 0, 0);
                __builtin_amdgcn_s_setprio(0);
            }
        }
        __syncthreads();
    }

    // epilogue: normalize and store bf16
#pragma unroll
    for (int qf = 0; qf < 2; ++qf)
#pragma unroll
        for (int r = 0; r < 4; ++r) {
            const float invl = 1.f / l_s[qf][r];
            const int q = qb * 128 + w * 32 + qf * 16 + lg * 4 + r;
#pragma unroll
            for (int df = 0; df < 4; ++df)
                AO[(size_t)(b * 1024 + q) * 2048 + hq * 64 + df * 16 + lm] = f2bf(acc_o[qf][df][r] * invl);
        }
}

// ---------------- host ----------------
extern "C" void kernel_launch(void* const* d_in, const int* in_sizes, int n_in,
                              void* d_out, int out_size, void* d_ws, size_t ws_size,
                              hipStream_t stream) {
    const float* X    = (const float*)d_in[0];  // [4096][1024]
    const float* Wqkv = (const float*)d_in[1];  // [1024][4096]
    const float* Wout = (const float*)d_in[2];  // [2048][1024]
    float* out = (float*)d_out;                 // [4096][1024]

    char* ws = (char*)d_ws;
    u16* Xb    = (u16*)(ws);                      // 8 MB  [4096][1024]
    u16* WqkvT = (u16*)(ws + (size_t)(8  << 20)); // 8 MB  [4096][1024]
    u16* WoutT = (u16*)(ws + (size_t)(16 << 20)); // 4 MB  [1024][2048]
    u16* QKV   = (u16*)(ws + (size_t)(20 << 20)); // 32 MB [4096][4096]
    u16* AO    = (u16*)(ws + (size_t)(52 << 20)); // 16 MB [4096][2048]

    k_cvt<<<4096, 256, 0, stream>>>(X, Xb, (4096 * 1024) / 4);
    k_transpose_cvt<<<dim3(128, 32), 256, 0, stream>>>(Wqkv, WqkvT, 1024, 4096);
    k_transpose_cvt<<<dim3(32, 64), 256, 0, stream>>>(Wout, WoutT, 2048, 1024);

    // QKV = Xb[4096,1024] @ WqkvT^T -> bf16 [4096][4096]
    k_gemm_nt<0><<<dim3(32, 32), 256, 0, stream>>>(Xb, WqkvT, QKV, 4096, 4096, 1024);

    // attention -> AO bf16 [4096][2048]
    k_attn<<<dim3(8, 32, 4), 256, 0, stream>>>(QKV, AO);

    // out = AO[4096,2048] @ WoutT^T -> f32 [4096][1024]
    k_gemm_nt<1><<<dim3(8, 32), 256, 0, stream>>>(AO, WoutT, out, 4096, 1024, 2048);
}

// Round 4
// 284.609 us; speedup vs baseline: 1.2196x; 1.0510x over previous
//
#include <hip/hip_runtime.h>

typedef unsigned short u16;
typedef unsigned int u32;
typedef float f32x4 __attribute__((ext_vector_type(4)));
typedef float f32x16 __attribute__((ext_vector_type(16)));
typedef __bf16 bf16x8 __attribute__((ext_vector_type(8)));
typedef short short8 __attribute__((ext_vector_type(8)));
typedef u16 u16x4 __attribute__((ext_vector_type(4)));
typedef float f32x4v __attribute__((ext_vector_type(4)));

#define DEV __device__ __forceinline__

DEV u16 f2bf(float f) {
    union { float f; unsigned u; } v; v.f = f;
    unsigned r = v.u + 0x7FFFu + ((v.u >> 16) & 1u);
    return (u16)(r >> 16);
}

DEV void gload_lds16(const u16* g, u16* l) {
    __builtin_amdgcn_global_load_lds(
        (const __attribute__((address_space(1))) void*)g,
        (__attribute__((address_space(3))) void*)l, 16, 0, 0);
}

// ---------------- convert fp32 -> bf16 (vectorized) ----------------
__global__ __launch_bounds__(256) void k_cvt(const float* __restrict__ in,
                                             u16* __restrict__ out, int n4) {
    int i = blockIdx.x * 256 + threadIdx.x;
    if (i >= n4) return;
    f32x4v v = reinterpret_cast<const f32x4v*>(in)[i];
    u16x4 o;
    o.x = f2bf(v.x); o.y = f2bf(v.y); o.z = f2bf(v.z); o.w = f2bf(v.w);
    reinterpret_cast<u16x4*>(out)[i] = o;
}

// ---------------- convert + transpose: in[R][C] f32 -> out[C][R] bf16 ----------------
__global__ __launch_bounds__(256) void k_transpose_cvt(const float* __restrict__ in,
                                                       u16* __restrict__ out,
                                                       int R, int C) {
    __shared__ float tile[32][33];
    const int c0 = blockIdx.x * 32, r0 = blockIdx.y * 32;
    const int tx = threadIdx.x & 31, ty = threadIdx.x >> 5;  // ty 0..7
#pragma unroll
    for (int i = 0; i < 32; i += 8)
        tile[ty + i][tx] = in[(size_t)(r0 + ty + i) * C + c0 + tx];
    __syncthreads();
#pragma unroll
    for (int i = 0; i < 32; i += 8)
        out[(size_t)(c0 + ty + i) * R + r0 + tx] = f2bf(tile[tx][ty + i]);
}

// ---------------- bf16 GEMM: C[M][N] = A[M][K] * Bt[N][K]^T ----------------
template <int OUTF>  // 0: bf16 out, 1: f32 out
__global__ __launch_bounds__(256) void k_gemm_nt(const u16* __restrict__ A,
                                                 const u16* __restrict__ Bt,
                                                 void* __restrict__ Cv,
                                                 int M, int N, int K) {
    __shared__ u16 lA[2][4096];  // [128][32]
    __shared__ u16 lB[2][4096];  // [128][32]
    const int t = threadIdx.x, l = t & 63, w = t >> 6;
    const int bm = blockIdx.y * 128, bn = blockIdx.x * 128;
    const int wr = w >> 1, wc = w & 1;
    const int lm = l & 15, lg = l >> 4;

    f32x4 acc[4][4] = {};

    const int nk = K >> 5;
    auto stage = [&](int buf, int kt) {
        const int k0 = kt << 5;
        const int kc = (l & 3) * 8;
        const int rsub = w * 16 + (l >> 2);
#pragma unroll
        for (int p = 0; p < 2; ++p) {
            const int row = p * 64 + rsub;
            gload_lds16(A + (size_t)(bm + row) * K + k0 + kc, &lA[buf][p * 2048 + w * 512]);
            gload_lds16(Bt + (size_t)(bn + row) * K + k0 + kc, &lB[buf][p * 2048 + w * 512]);
        }
    };

    stage(0, 0);
    __syncthreads();
    for (int kt = 0; kt < nk; ++kt) {
        const int buf = kt & 1;
        if (kt + 1 < nk) stage(buf ^ 1, kt + 1);
        bf16x8 af[4], bfr[4];
#pragma unroll
        for (int i = 0; i < 4; ++i) {
            af[i]  = *reinterpret_cast<const bf16x8*>(&lA[buf][(wr * 64 + i * 16 + lm) * 32 + lg * 8]);
            bfr[i] = *reinterpret_cast<const bf16x8*>(&lB[buf][(wc * 64 + i * 16 + lm) * 32 + lg * 8]);
        }
        __builtin_amdgcn_s_setprio(1);
#pragma unroll
        for (int mi = 0; mi < 4; ++mi)
#pragma unroll
            for (int ni = 0; ni < 4; ++ni)
                acc[mi][ni] = __builtin_amdgcn_mfma_f32_16x16x32_bf16(af[mi], bfr[ni], acc[mi][ni], 0, 0, 0);
        __builtin_amdgcn_s_setprio(0);
        __syncthreads();
    }

#pragma unroll
    for (int mi = 0; mi < 4; ++mi)
#pragma unroll
        for (int ni = 0; ni < 4; ++ni)
#pragma unroll
            for (int r = 0; r < 4; ++r) {
                const int row = bm + wr * 64 + mi * 16 + lg * 4 + r;
                const int col = bn + wc * 64 + ni * 16 + lm;
                if (OUTF)
                    reinterpret_cast<float*>(Cv)[(size_t)row * N + col] = acc[mi][ni][r];
                else
                    reinterpret_cast<u16*>(Cv)[(size_t)row * N + col] = f2bf(acc[mi][ni][r]);
            }
}

// ---------------- flash attention, swapped-operand 32x32 structure ----------------
// qkv: [4096][4096] bf16 rows=b*1024+s; cols: [0,2048) Q, [2048,3072) K, [3072,4096) V
// AO:  [4096][2048] bf16 (b,s,hq,d)
// Block: 512 thr (8 waves), covers 256 q rows of one (b,hq). Wave w owns q rows
// w*32..+31. Swapped QK^T: sc = mfma(K_frag, Q_frag) -> lane column = q (lo5),
// rows = kv (crow(r,hi)); softmax over kv is lane-local + one shfl_xor(32).
// PV: A-frag packed in-register from p (cvt_pk); the crow 4-run interleave is
// absorbed by staging V^T with kv bits2<->3 swapped (sigma), so no shuffles.
// Accumulator rows = crow(q); per-tile scl and final 1/l broadcast via lSc.
__global__ __launch_bounds__(512, 4) void k_attn(const u16* __restrict__ qkv,
                                                 u16* __restrict__ AO) {
    __shared__ u16 lK[4096];    // [64 kv][64 d], chunk ^= (row&7)
    __shared__ u16 lVT[4096];   // [64 d][64 kv_sigma], chunk ^= (d^(d>>3))&7
    __shared__ float lSc[8][32];

    const int t = threadIdx.x, l = t & 63, w = t >> 6;
    const int lo5 = l & 31, hi = l >> 5;
    const int qb = blockIdx.x;   // 0..3 (256-row q block)
    const int hq = blockIdx.y;   // 0..31
    const int b  = blockIdx.z;   // 0..3
    const int hkv = hq >> 1;
    const float L2E = 1.44269504088896f;
    const float slope2 = exp2f(-0.25f * (float)(hq + 1)) * L2E;
    const float scale2 = 0.125f * L2E;
    const size_t RS = 4096;
    const u16* Qg = qkv + (size_t)(b * 1024 + qb * 256) * RS + hq * 64;
    const u16* Kg = qkv + (size_t)(b * 1024) * RS + 2048 + hkv * 64;
    const u16* Vg = qkv + (size_t)(b * 1024) * RS + 3072 + hkv * 64;

    const int q = qb * 256 + w * 32 + lo5;   // lane's q column

    // Q fragments (B-operand): lane holds Q[q=lo5-col][d = ks*16 + hi*8 + j]
    bf16x8 qfr[4];
#pragma unroll
    for (int ks = 0; ks < 4; ++ks)
        qfr[ks] = *reinterpret_cast<const bf16x8*>(
            Qg + (size_t)(w * 32 + lo5) * RS + ks * 16 + hi * 8);

    f32x16 acc0 = {}, acc1 = {};   // O[q=crow][d = df*32 + lo5]
    float m_ = -3.0e38f, l_ = 0.f;

    const int nt = (qb + 1) * 4;
    const int kbd = (qb * 256 + w * 32 + 31) >> 6;  // warp's diagonal tile

    for (int kb = 0; kb < nt; ++kb) {
        {   // stage K [64][64] via gload_lds, pre-swizzled source chunk
            const int row = t >> 3;
            const int ch = (t & 7) ^ (row & 7);
            gload_lds16(Kg + (size_t)(kb * 64 + row) * RS + ch * 8, &lK[w * 512]);
        }
        {   // stage V^T [64 d][64 kv_sigma] via register transpose
            const int kv = t >> 3, d0 = (t & 7) * 8;
            short8 v = *reinterpret_cast<const short8*>(Vg + (size_t)(kb * 64 + kv) * RS + d0);
            const int kvs = (kv & ~12) | ((kv & 4) << 1) | ((kv & 8) >> 1);  // swap bits 2,3
#pragma unroll
            for (int j = 0; j < 8; ++j) {
                const int d = d0 + j;
                const int key = (d ^ (d >> 3)) & 7;
                lVT[d * 64 + (((kvs >> 3) ^ key) & 7) * 8 + (kvs & 7)] = (u16)v[j];
            }
        }
        __syncthreads();

        if (kb <= kbd) {
            // QK^T (swapped): sc[kblk] rows = kv crow, cols = q
            f32x16 sc0 = {}, sc1 = {};
#pragma unroll
            for (int ks = 0; ks < 4; ++ks) {
                const int csw = ((ks * 2 + hi) ^ (lo5 & 7)) * 8;
                bf16x8 ka0 = *reinterpret_cast<const bf16x8*>(&lK[lo5 * 64 + csw]);
                bf16x8 ka1 = *reinterpret_cast<const bf16x8*>(&lK[(32 + lo5) * 64 + csw]);
                __builtin_amdgcn_s_setprio(1);
                sc0 = __builtin_amdgcn_mfma_f32_32x32x16_bf16(ka0, qfr[ks], sc0, 0, 0, 0);
                sc1 = __builtin_amdgcn_mfma_f32_32x32x16_bf16(ka1, qfr[ks], sc1, 0, 0, 0);
                __builtin_amdgcn_s_setprio(0);
            }
            // bias + mask (exp2 domain), all lane-local
            float s[32];
            const float b0 = slope2 * (float)(kb * 64 + 4 * hi - q);
            const float b1 = slope2 * (float)(kb * 64 + 32 + 4 * hi - q);
#pragma unroll
            for (int r = 0; r < 16; ++r) {
                const int Cr = (r & 3) + 8 * (r >> 2);
                s[r]      = fmaf(sc0[r], scale2, fmaf(slope2, (float)Cr, b0));
                s[16 + r] = fmaf(sc1[r], scale2, fmaf(slope2, (float)Cr, b1));
            }
            if (kb == kbd) {
                const int qr0 = q - kb * 64 - 4 * hi;
#pragma unroll
                for (int r = 0; r < 16; ++r) {
                    const int Cr = (r & 3) + 8 * (r >> 2);
                    if (Cr > qr0)      s[r]      = -3.0e38f;
                    if (Cr + 32 > qr0) s[16 + r] = -3.0e38f;
                }
            }
            // row max: in-register tree + one cross-half swap
            float tm[16];
#pragma unroll
            for (int i = 0; i < 16; ++i) tm[i] = fmaxf(s[i], s[16 + i]);
#pragma unroll
            for (int i = 0; i < 8; ++i) tm[i] = fmaxf(tm[i], tm[8 + i]);
#pragma unroll
            for (int i = 0; i < 4; ++i) tm[i] = fmaxf(tm[i], tm[4 + i]);
            float mx = fmaxf(fmaxf(tm[0], tm[1]), fmaxf(tm[2], tm[3]));
            mx = fmaxf(mx, __shfl_xor(mx, 32));
            const float mnew = fmaxf(m_, mx);
            const float sclf = exp2f(m_ - mnew);
            m_ = mnew;
#pragma unroll
            for (int i = 0; i < 32; ++i) s[i] = exp2f(s[i] - mnew);
            float ts[16];
#pragma unroll
            for (int i = 0; i < 16; ++i) ts[i] = s[i] + s[16 + i];
#pragma unroll
            for (int i = 0; i < 8; ++i) ts[i] += ts[8 + i];
#pragma unroll
            for (int i = 0; i < 4; ++i) ts[i] += ts[4 + i];
            float sum = (ts[0] + ts[1]) + (ts[2] + ts[3]);
            sum += __shfl_xor(sum, 32);
            l_ = l_ * sclf + sum;
            // broadcast per-q scl to accumulator rows (crow layout)
            lSc[w][lo5] = sclf;
            asm volatile("s_waitcnt lgkmcnt(0)" ::: "memory");
            float rs_[16];
#pragma unroll
            for (int r = 0; r < 16; ++r) {
                const int Cr = (r & 3) + 8 * (r >> 2);
                rs_[r] = lSc[w][Cr + 4 * hi];
            }
#pragma unroll
            for (int r = 0; r < 16; ++r) { acc0[r] *= rs_[r]; acc1[r] *= rs_[r]; }
            // pack P into PV A-frags (pure in-register; sigma on V absorbs order)
            u32 pw[16];
#pragma unroll
            for (int s4 = 0; s4 < 4; ++s4) {
                const int off = (s4 >> 1) * 16 + (s4 & 1) * 8;
#pragma unroll
                for (int j = 0; j < 4; ++j) {
                    u32 o;
                    asm("v_cvt_pk_bf16_f32 %0, %1, %2"
                        : "=v"(o) : "v"(s[off + 2 * j]), "v"(s[off + 2 * j + 1]));
                    pw[s4 * 4 + j] = o;
                }
            }
            // PV: acc[df] += P * V  (B-frag from sigma-ordered lVT)
            const int key0 = (lo5 ^ (lo5 >> 3)) & 7;
            const int key1 = ((32 + lo5) ^ ((32 + lo5) >> 3)) & 7;
#pragma unroll
            for (int s4 = 0; s4 < 4; ++s4) {
                bf16x8 pa;
                u32* paw = reinterpret_cast<u32*>(&pa);
                paw[0] = pw[s4 * 4 + 0]; paw[1] = pw[s4 * 4 + 1];
                paw[2] = pw[s4 * 4 + 2]; paw[3] = pw[s4 * 4 + 3];
                const int cl = s4 * 2 + hi;
                bf16x8 va0 = *reinterpret_cast<const bf16x8*>(&lVT[lo5 * 64 + ((cl ^ key0) & 7) * 8]);
                bf16x8 va1 = *reinterpret_cast<const bf16x8*>(&lVT[(32 + lo5) * 64 + ((cl ^ key1) & 7) * 8]);
                __builtin_amdgcn_s_setprio(1);
                acc0 = __builtin_amdgcn_mfma_f32_32x32x16_bf16(pa, va0, acc0, 0, 0, 0);
                acc1 = __builtin_amdgcn_mfma_f32_32x32x16_bf16(pa, va1, acc1, 0, 0, 0);
                __builtin_amdgcn_s_setprio(0);
            }
        }
        __syncthreads();
    }

    // epilogue: broadcast 1/l to crow layout, store coalesced 64B runs
    lSc[w][lo5] = 1.0f / l_;
    asm volatile("s_waitcnt lgkmcnt(0)" ::: "memory");
    float rl[16];
#pragma unroll
    for (int r = 0; r < 16; ++r) {
        const int Cr = (r & 3) + 8 * (r >> 2);
        rl[r] = lSc[w][Cr + 4 * hi];
    }
    u16* AOp = AO + (size_t)(b * 1024 + qb * 256 + w * 32) * 2048 + hq * 64;
#pragma unroll
    for (int r = 0; r < 16; ++r) {
        const int Cr = (r & 3) + 8 * (r >> 2);
        const size_t rowoff = (size_t)(Cr + 4 * hi) * 2048;
        AOp[rowoff + lo5]      = f2bf(acc0[r] * rl[r]);
        AOp[rowoff + 32 + lo5] = f2bf(acc1[r] * rl[r]);
    }
}

// ---------------- host ----------------
extern "C" void kernel_launch(void* const* d_in, const int* in_sizes, int n_in,
                              void* d_out, int out_size, void* d_ws, size_t ws_size,
                              hipStream_t stream) {
    const float* X    = (const float*)d_in[0];  // [4096][1024]
    const float* Wqkv = (const float*)d_in[1];  // [1024][4096]
    const float* Wout = (const float*)d_in[2];  // [2048][1024]
    float* out = (float*)d_out;                 // [4096][1024]

    char* ws = (char*)d_ws;
    u16* Xb    = (u16*)(ws);                      // 8 MB  [4096][1024]
    u16* WqkvT = (u16*)(ws + (size_t)(8  << 20)); // 8 MB  [4096][1024]
    u16* WoutT = (u16*)(ws + (size_t)(16 << 20)); // 4 MB  [1024][2048]
    u16* QKV   = (u16*)(ws + (size_t)(20 << 20)); // 32 MB [4096][4096]
    u16* AO    = (u16*)(ws + (size_t)(52 << 20)); // 16 MB [4096][2048]

    k_cvt<<<4096, 256, 0, stream>>>(X, Xb, (4096 * 1024) / 4);
    k_transpose_cvt<<<dim3(128, 32), 256, 0, stream>>>(Wqkv, WqkvT, 1024, 4096);
    k_transpose_cvt<<<dim3(32, 64), 256, 0, stream>>>(Wout, WoutT, 2048, 1024);

    // QKV = Xb[4096,1024] @ WqkvT^T -> bf16 [4096][4096]
    k_gemm_nt<0><<<dim3(32, 32), 256, 0, stream>>>(Xb, WqkvT, QKV, 4096, 4096, 1024);

    // attention -> AO bf16 [4096][2048]
    k_attn<<<dim3(4, 32, 4), 512, 0, stream>>>(QKV, AO);

    // out = AO[4096,2048] @ WoutT^T -> f32 [4096][1024]
    k_gemm_nt<1><<<dim3(8, 32), 256, 0, stream>>>(AO, WoutT, out, 4096, 1024, 2048);
}

// Round 5
// 264.466 us; speedup vs baseline: 1.3125x; 1.0762x over previous
//
#include <hip/hip_runtime.h>

typedef unsigned short u16;
typedef unsigned int u32;
typedef float f32x4 __attribute__((ext_vector_type(4)));
typedef float f32x16 __attribute__((ext_vector_type(16)));
typedef __bf16 bf16x8 __attribute__((ext_vector_type(8)));
typedef short short8 __attribute__((ext_vector_type(8)));
typedef u16 u16x4 __attribute__((ext_vector_type(4)));
typedef float f32x4v __attribute__((ext_vector_type(4)));

#define DEV __device__ __forceinline__

DEV u16 f2bf(float f) {
    union { float f; unsigned u; } v; v.f = f;
    unsigned r = v.u + 0x7FFFu + ((v.u >> 16) & 1u);
    return (u16)(r >> 16);
}

DEV void gload_lds16(const u16* g, u16* l) {
    __builtin_amdgcn_global_load_lds(
        (const __attribute__((address_space(1))) void*)g,
        (__attribute__((address_space(3))) void*)l, 16, 0, 0);
}

// ---------------- convert fp32 -> bf16 (vectorized) ----------------
__global__ __launch_bounds__(256) void k_cvt(const float* __restrict__ in,
                                             u16* __restrict__ out, int n4) {
    int i = blockIdx.x * 256 + threadIdx.x;
    if (i >= n4) return;
    f32x4v v = reinterpret_cast<const f32x4v*>(in)[i];
    u16x4 o;
    o.x = f2bf(v.x); o.y = f2bf(v.y); o.z = f2bf(v.z); o.w = f2bf(v.w);
    reinterpret_cast<u16x4*>(out)[i] = o;
}

// ---------------- convert + transpose: in[R][C] f32 -> out[C][R] bf16 ----------------
__global__ __launch_bounds__(256) void k_transpose_cvt(const float* __restrict__ in,
                                                       u16* __restrict__ out,
                                                       int R, int C) {
    __shared__ float tile[32][33];
    const int c0 = blockIdx.x * 32, r0 = blockIdx.y * 32;
    const int tx = threadIdx.x & 31, ty = threadIdx.x >> 5;  // ty 0..7
#pragma unroll
    for (int i = 0; i < 32; i += 8)
        tile[ty + i][tx] = in[(size_t)(r0 + ty + i) * C + c0 + tx];
    __syncthreads();
#pragma unroll
    for (int i = 0; i < 32; i += 8)
        out[(size_t)(c0 + ty + i) * R + r0 + tx] = f2bf(tile[tx][ty + i]);
}

// ---------------- bf16 GEMM: C[M][N] = A[M][K] * Bt[N][K]^T ----------------
template <int OUTF>  // 0: bf16 out, 1: f32 out
__global__ __launch_bounds__(256) void k_gemm_nt(const u16* __restrict__ A,
                                                 const u16* __restrict__ Bt,
                                                 void* __restrict__ Cv,
                                                 int M, int N, int K) {
    __shared__ u16 lA[2][4096];  // [128][32]
    __shared__ u16 lB[2][4096];  // [128][32]
    const int t = threadIdx.x, l = t & 63, w = t >> 6;
    const int bm = blockIdx.y * 128, bn = blockIdx.x * 128;
    const int wr = w >> 1, wc = w & 1;
    const int lm = l & 15, lg = l >> 4;

    f32x4 acc[4][4] = {};

    const int nk = K >> 5;
    auto stage = [&](int buf, int kt) {
        const int k0 = kt << 5;
        const int kc = (l & 3) * 8;
        const int rsub = w * 16 + (l >> 2);
#pragma unroll
        for (int p = 0; p < 2; ++p) {
            const int row = p * 64 + rsub;
            gload_lds16(A + (size_t)(bm + row) * K + k0 + kc, &lA[buf][p * 2048 + w * 512]);
            gload_lds16(Bt + (size_t)(bn + row) * K + k0 + kc, &lB[buf][p * 2048 + w * 512]);
        }
    };

    stage(0, 0);
    __syncthreads();
    for (int kt = 0; kt < nk; ++kt) {
        const int buf = kt & 1;
        if (kt + 1 < nk) stage(buf ^ 1, kt + 1);
        bf16x8 af[4], bfr[4];
#pragma unroll
        for (int i = 0; i < 4; ++i) {
            af[i]  = *reinterpret_cast<const bf16x8*>(&lA[buf][(wr * 64 + i * 16 + lm) * 32 + lg * 8]);
            bfr[i] = *reinterpret_cast<const bf16x8*>(&lB[buf][(wc * 64 + i * 16 + lm) * 32 + lg * 8]);
        }
        __builtin_amdgcn_s_setprio(1);
#pragma unroll
        for (int mi = 0; mi < 4; ++mi)
#pragma unroll
            for (int ni = 0; ni < 4; ++ni)
                acc[mi][ni] = __builtin_amdgcn_mfma_f32_16x16x32_bf16(af[mi], bfr[ni], acc[mi][ni], 0, 0, 0);
        __builtin_amdgcn_s_setprio(0);
        __syncthreads();
    }

#pragma unroll
    for (int mi = 0; mi < 4; ++mi)
#pragma unroll
        for (int ni = 0; ni < 4; ++ni)
#pragma unroll
            for (int r = 0; r < 4; ++r) {
                const int row = bm + wr * 64 + mi * 16 + lg * 4 + r;
                const int col = bn + wc * 64 + ni * 16 + lm;
                if (OUTF)
                    reinterpret_cast<float*>(Cv)[(size_t)row * N + col] = acc[mi][ni][r];
                else
                    reinterpret_cast<u16*>(Cv)[(size_t)row * N + col] = f2bf(acc[mi][ni][r]);
            }
}

// ---------------- flash attention, swapped-operand 32x32, double-buffered ----------------
// qkv: [4096][4096] bf16 rows=b*1024+s; cols: [0,2048) Q, [2048,3072) K, [3072,4096) V
// AO:  [4096][2048] bf16 (b,s,hq,d)
// 512 thr (8 waves) cover 256 q rows of one (b,hq). Swapped QK^T: lane col = q.
// Double-buffered K/V staging: next tile's gload_lds(K) + global->reg V loads
// issued BEFORE compute; V ds_writes after compute; one barrier per tile.
// Flat-grid remap pairs heavy/light qb blocks (3,0)/(1,2) on the same CU.
__global__ __launch_bounds__(512, 4) void k_attn(const u16* __restrict__ qkv,
                                                 u16* __restrict__ AO) {
    __shared__ u16 lK[2][4096];    // [64 kv][64 d], chunk ^= (row&7)
    __shared__ u16 lVT[2][4096];   // [64 d][64 kv_sigma], chunk ^= (d^(d>>3))&7
    __shared__ float lSc[8][32];

    const int t = threadIdx.x, l = t & 63, w = t >> 6;
    const int lo5 = l & 31, hi = l >> 5;
    // balance remap: fid i and i+256 land on the same CU (round-robin); give
    // them qb pairs (3,0) / (1,2) so every CU gets 20 tile-slots.
    const int fid = blockIdx.x;
    const int half = fid >> 8, idx = fid & 255;
    const int j = idx & 1, hb = idx >> 1;
    const int hq = hb >> 2, b = hb & 3;
    const int qb = half ? (j ? 2 : 0) : (j ? 1 : 3);
    const int hkv = hq >> 1;
    const float L2E = 1.44269504088896f;
    const float slope2 = exp2f(-0.25f * (float)(hq + 1)) * L2E;
    const float scale2 = 0.125f * L2E;
    const size_t RS = 4096;
    const u16* Qg = qkv + (size_t)(b * 1024 + qb * 256) * RS + hq * 64;
    const u16* Kg = qkv + (size_t)(b * 1024) * RS + 2048 + hkv * 64;
    const u16* Vg = qkv + (size_t)(b * 1024) * RS + 3072 + hkv * 64;

    const int q = qb * 256 + w * 32 + lo5;   // lane's q column

    // Q fragments (B-operand): lane holds Q[q=lo5-col][d = ks*16 + hi*8 + j]
    bf16x8 qfr[4];
#pragma unroll
    for (int ks = 0; ks < 4; ++ks)
        qfr[ks] = *reinterpret_cast<const bf16x8*>(
            Qg + (size_t)(w * 32 + lo5) * RS + ks * 16 + hi * 8);

    f32x16 acc0 = {}, acc1 = {};   // O[q=crow][d = df*32 + lo5]
    float m_ = -3.0e38f, l_ = 0.f;

    const int nt = (qb + 1) * 4;
    const int kbd = (qb * 256 + w * 32 + 31) >> 6;  // wave's diagonal tile

    auto stageK = [&](int buf, int kb) {
        const int row = t >> 3;
        const int ch = (t & 7) ^ (row & 7);
        gload_lds16(Kg + (size_t)(kb * 64 + row) * RS + ch * 8, &lK[buf][w * 512]);
    };
    // V: tid<256, each thread 2 kv rows x 8 d; paired u32 LDS writes
    const int kvp = t >> 3, vd0 = (t & 7) * 8;
    auto loadV = [&](int kb, short8& a, short8& b2) {
        a  = *reinterpret_cast<const short8*>(Vg + (size_t)(kb * 64 + kvp * 2) * RS + vd0);
        b2 = *reinterpret_cast<const short8*>(Vg + (size_t)(kb * 64 + kvp * 2 + 1) * RS + vd0);
    };
    auto writeV = [&](int buf, short8 a, short8 b2) {
        const int kv0 = kvp * 2;
        const int kvs0 = (kv0 & ~12) | ((kv0 & 4) << 1) | ((kv0 & 8) >> 1);  // sigma: swap bits 2,3
#pragma unroll
        for (int jj = 0; jj < 8; ++jj) {
            const int d = vd0 + jj;
            const int key = (d ^ (d >> 3)) & 7;
            const u32 val = (u32)(u16)a[jj] | ((u32)(u16)b2[jj] << 16);
            *reinterpret_cast<u32*>(
                &lVT[buf][d * 64 + (((kvs0 >> 3) ^ key) & 7) * 8 + (kvs0 & 7)]) = val;
        }
    };

    short8 vA, vB;
    // prologue: stage tile 0
    stageK(0, 0);
    if (t < 256) { loadV(0, vA, vB); writeV(0, vA, vB); }
    __syncthreads();

    for (int kb = 0; kb < nt; ++kb) {
        const int buf = kb & 1;
        const bool pre = (kb + 1 < nt);
        if (pre) {
            stageK(buf ^ 1, kb + 1);
            if (t < 256) loadV(kb + 1, vA, vB);
        }

        if (kb <= kbd) {
            // QK^T (swapped): sc rows = kv crow, cols = q
            f32x16 sc0 = {}, sc1 = {};
#pragma unroll
            for (int ks = 0; ks < 4; ++ks) {
                const int csw = ((ks * 2 + hi) ^ (lo5 & 7)) * 8;
                bf16x8 ka0 = *reinterpret_cast<const bf16x8*>(&lK[buf][lo5 * 64 + csw]);
                bf16x8 ka1 = *reinterpret_cast<const bf16x8*>(&lK[buf][(32 + lo5) * 64 + csw]);
                __builtin_amdgcn_s_setprio(1);
                sc0 = __builtin_amdgcn_mfma_f32_32x32x16_bf16(ka0, qfr[ks], sc0, 0, 0, 0);
                sc1 = __builtin_amdgcn_mfma_f32_32x32x16_bf16(ka1, qfr[ks], sc1, 0, 0, 0);
                __builtin_amdgcn_s_setprio(0);
            }
            // bias + mask (exp2 domain), all lane-local
            float s[32];
            const float b0 = slope2 * (float)(kb * 64 + 4 * hi - q);
            const float b1 = slope2 * (float)(kb * 64 + 32 + 4 * hi - q);
#pragma unroll
            for (int r = 0; r < 16; ++r) {
                const int Cr = (r & 3) + 8 * (r >> 2);
                s[r]      = fmaf(sc0[r], scale2, fmaf(slope2, (float)Cr, b0));
                s[16 + r] = fmaf(sc1[r], scale2, fmaf(slope2, (float)Cr, b1));
            }
            if (kb == kbd) {
                const int qr0 = q - kb * 64 - 4 * hi;
#pragma unroll
                for (int r = 0; r < 16; ++r) {
                    const int Cr = (r & 3) + 8 * (r >> 2);
                    if (Cr > qr0)      s[r]      = -3.0e38f;
                    if (Cr + 32 > qr0) s[16 + r] = -3.0e38f;
                }
            }
            // row max: in-register tree + one cross-half swap
            float tm[16];
#pragma unroll
            for (int i = 0; i < 16; ++i) tm[i] = fmaxf(s[i], s[16 + i]);
#pragma unroll
            for (int i = 0; i < 8; ++i) tm[i] = fmaxf(tm[i], tm[8 + i]);
#pragma unroll
            for (int i = 0; i < 4; ++i) tm[i] = fmaxf(tm[i], tm[4 + i]);
            float mx = fmaxf(fmaxf(tm[0], tm[1]), fmaxf(tm[2], tm[3]));
            mx = fmaxf(mx, __shfl_xor(mx, 32));
            const float mnew = fmaxf(m_, mx);
            const float sclf = exp2f(m_ - mnew);
            m_ = mnew;
#pragma unroll
            for (int i = 0; i < 32; ++i) s[i] = exp2f(s[i] - mnew);
            float ts[16];
#pragma unroll
            for (int i = 0; i < 16; ++i) ts[i] = s[i] + s[16 + i];
#pragma unroll
            for (int i = 0; i < 8; ++i) ts[i] += ts[8 + i];
#pragma unroll
            for (int i = 0; i < 4; ++i) ts[i] += ts[4 + i];
            float sum = (ts[0] + ts[1]) + (ts[2] + ts[3]);
            sum += __shfl_xor(sum, 32);
            l_ = l_ * sclf + sum;
            // broadcast per-q scl to accumulator rows (crow layout)
            lSc[w][lo5] = sclf;
            asm volatile("s_waitcnt lgkmcnt(0)" ::: "memory");
            float rs_[16];
#pragma unroll
            for (int r = 0; r < 16; ++r) {
                const int Cr = (r & 3) + 8 * (r >> 2);
                rs_[r] = lSc[w][Cr + 4 * hi];
            }
#pragma unroll
            for (int r = 0; r < 16; ++r) { acc0[r] *= rs_[r]; acc1[r] *= rs_[r]; }
            // pack P into PV A-frags (pure in-register; sigma on V absorbs order)
            u32 pw[16];
#pragma unroll
            for (int s4 = 0; s4 < 4; ++s4) {
                const int off = (s4 >> 1) * 16 + (s4 & 1) * 8;
#pragma unroll
                for (int jj = 0; jj < 4; ++jj) {
                    u32 o;
                    asm("v_cvt_pk_bf16_f32 %0, %1, %2"
                        : "=v"(o) : "v"(s[off + 2 * jj]), "v"(s[off + 2 * jj + 1]));
                    pw[s4 * 4 + jj] = o;
                }
            }
            // PV: acc[df] += P * V  (B-frag from sigma-ordered lVT)
            const int key0 = (lo5 ^ (lo5 >> 3)) & 7;
            const int key1 = ((32 + lo5) ^ ((32 + lo5) >> 3)) & 7;
#pragma unroll
            for (int s4 = 0; s4 < 4; ++s4) {
                bf16x8 pa;
                u32* paw = reinterpret_cast<u32*>(&pa);
                paw[0] = pw[s4 * 4 + 0]; paw[1] = pw[s4 * 4 + 1];
                paw[2] = pw[s4 * 4 + 2]; paw[3] = pw[s4 * 4 + 3];
                const int cl = s4 * 2 + hi;
                bf16x8 va0 = *reinterpret_cast<const bf16x8*>(&lVT[buf][lo5 * 64 + ((cl ^ key0) & 7) * 8]);
                bf16x8 va1 = *reinterpret_cast<const bf16x8*>(&lVT[buf][(32 + lo5) * 64 + ((cl ^ key1) & 7) * 8]);
                __builtin_amdgcn_s_setprio(1);
                acc0 = __builtin_amdgcn_mfma_f32_32x32x16_bf16(pa, va0, acc0, 0, 0, 0);
                acc1 = __builtin_amdgcn_mfma_f32_32x32x16_bf16(pa, va1, acc1, 0, 0, 0);
                __builtin_amdgcn_s_setprio(0);
            }
        }

        if (pre && t < 256) writeV(buf ^ 1, vA, vB);
        __syncthreads();
    }

    // epilogue: broadcast 1/l to crow layout, store coalesced 64B runs
    lSc[w][lo5] = 1.0f / l_;
    asm volatile("s_waitcnt lgkmcnt(0)" ::: "memory");
    float rl[16];
#pragma unroll
    for (int r = 0; r < 16; ++r) {
        const int Cr = (r & 3) + 8 * (r >> 2);
        rl[r] = lSc[w][Cr + 4 * hi];
    }
    u16* AOp = AO + (size_t)(b * 1024 + qb * 256 + w * 32) * 2048 + hq * 64;
#pragma unroll
    for (int r = 0; r < 16; ++r) {
        const int Cr = (r & 3) + 8 * (r >> 2);
        const size_t rowoff = (size_t)(Cr + 4 * hi) * 2048;
        AOp[rowoff + lo5]      = f2bf(acc0[r] * rl[r]);
        AOp[rowoff + 32 + lo5] = f2bf(acc1[r] * rl[r]);
    }
}

// ---------------- host ----------------
extern "C" void kernel_launch(void* const* d_in, const int* in_sizes, int n_in,
                              void* d_out, int out_size, void* d_ws, size_t ws_size,
                              hipStream_t stream) {
    const float* X    = (const float*)d_in[0];  // [4096][1024]
    const float* Wqkv = (const float*)d_in[1];  // [1024][4096]
    const float* Wout = (const float*)d_in[2];  // [2048][1024]
    float* out = (float*)d_out;                 // [4096][1024]

    char* ws = (char*)d_ws;
    u16* Xb    = (u16*)(ws);                      // 8 MB  [4096][1024]
    u16* WqkvT = (u16*)(ws + (size_t)(8  << 20)); // 8 MB  [4096][1024]
    u16* WoutT = (u16*)(ws + (size_t)(16 << 20)); // 4 MB  [1024][2048]
    u16* QKV   = (u16*)(ws + (size_t)(20 << 20)); // 32 MB [4096][4096]
    u16* AO    = (u16*)(ws + (size_t)(52 << 20)); // 16 MB [4096][2048]

    k_cvt<<<4096, 256, 0, stream>>>(X, Xb, (4096 * 1024) / 4);
    k_transpose_cvt<<<dim3(128, 32), 256, 0, stream>>>(Wqkv, WqkvT, 1024, 4096);
    k_transpose_cvt<<<dim3(32, 64), 256, 0, stream>>>(Wout, WoutT, 2048, 1024);

    // QKV = Xb[4096,1024] @ WqkvT^T -> bf16 [4096][4096]
    k_gemm_nt<0><<<dim3(32, 32), 256, 0, stream>>>(Xb, WqkvT, QKV, 4096, 4096, 1024);

    // attention -> AO bf16 [4096][2048]
    k_attn<<<dim3(512), 512, 0, stream>>>(QKV, AO);

    // out = AO[4096,2048] @ WoutT^T -> f32 [4096][1024]
    k_gemm_nt<1><<<dim3(8, 32), 256, 0, stream>>>(AO, WoutT, out, 4096, 1024, 2048);
}